// Round 1
// baseline (598.033 us; speedup 1.0000x reference)
//
#include <hip/hip_runtime.h>

// Problem constants
constexpr int Bc  = 4;
constexpr int Sc  = 384;
constexpr int Dc  = 300;
constexpr int Ec  = 50;
constexpr int HDc = 150;          // D / L
constexpr int WHC = 2*HDc + Ec;   // 350, Wh row length

// ---------------------------------------------------------------------------
// prep: column sums of Wh_e, Wh_1, Wh_2 and sum(bh) into small buffer
// layout (floats): [0..49] we_colsum, [64..213] w1_colsum, [224..373] w2_colsum,
//                  [384] sum(bh)
// ---------------------------------------------------------------------------
__global__ void prep_kernel(const float* __restrict__ Wh,
                            const float* __restrict__ bh,
                            float* __restrict__ sm) {
    int t = threadIdx.x;  // 512 threads
    if (t < Ec) {
        float s = 0.f;
        for (int e = 0; e < Ec; ++e) s += Wh[e*WHC + t];
        sm[t] = s;
    } else if (t >= 64 && t < 64 + HDc) {
        int h = t - 64;
        float s = 0.f;
        for (int e = 0; e < Ec; ++e) s += Wh[e*WHC + Ec + h];
        sm[t] = s;
    } else if (t >= 224 && t < 224 + HDc) {
        int h = t - 224;
        float s = 0.f;
        for (int e = 0; e < Ec; ++e) s += Wh[e*WHC + Ec + HDc + h];
        sm[t] = s;
    } else if (t == 384) {
        float s = 0.f;
        for (int e = 0; e < Ec; ++e) s += bh[e];
        sm[t] = s;
    }
}

// ---------------------------------------------------------------------------
// reduce_adj: one pass over adj (B,S,S,E).
//   A0[row]   = (Σ_e adj[row,e]) / E          (scaled adjacency for layer 0)
//   wadj[row] =  Σ_e adj[row,e]*we_colsum[e]  (Σ_e of layer-1 edge_part)
// ---------------------------------------------------------------------------
__global__ __launch_bounds__(256)
void reduce_adj(const float* __restrict__ adj, const float* __restrict__ sm,
                float* __restrict__ A0, float* __restrict__ wadj) {
    __shared__ float wec[Ec];
    int t = threadIdx.x;
    if (t < Ec) wec[t] = sm[t];
    __syncthreads();
    int row = blockIdx.x * 256 + t;
    const int nrows = Bc * Sc * Sc;
    if (row < nrows) {
        const float2* p = (const float2*)(adj + (long)row * Ec);
        float s = 0.f, w = 0.f;
        #pragma unroll
        for (int i = 0; i < Ec/2; ++i) {
            float2 v = p[i];
            s += v.x + v.y;
            w += v.x * wec[2*i] + v.y * wec[2*i + 1];
        }
        A0[row]   = s * (1.0f / Ec);
        wadj[row] = w;
    }
}

// ---------------------------------------------------------------------------
// Generic tiled fp32 GEMM: C[b] = A[b] @ B(+T) [+ Dm[b]] [+ bscale*bias] [relu]
// A: (M,K) row-major, batch stride strideA
// B: transB=0 -> (K,N) row-major (stride strideB); transB=1 -> (N,K) row-major
// ---------------------------------------------------------------------------
#define TM 64
#define TN 64
#define TK 16
__global__ __launch_bounds__(256)
void gemm_kernel(const float* __restrict__ A, const float* __restrict__ Bm,
                 const float* __restrict__ Dm, const float* __restrict__ bias,
                 float* __restrict__ C,
                 int M, int N, int K,
                 long strideA, long strideB, long strideD, long strideC,
                 int transB, float bscale, int relu) {
    int b = blockIdx.z;
    A += (long)b * strideA;
    Bm += (long)b * strideB;
    const float* Dp = Dm ? Dm + (long)b * strideD : nullptr;
    C += (long)b * strideC;

    __shared__ float As[TK][TM + 1];
    __shared__ float Bs[TK][TN + 1];

    int tid = threadIdx.x;
    int tx = tid % 16, ty = tid / 16;
    int m0 = blockIdx.y * TM, n0 = blockIdx.x * TN;

    float acc[4][4] = {};

    for (int k0 = 0; k0 < K; k0 += TK) {
        // A tile (TM x TK)
        {
            int kl = tid % TK;
            int mbase = tid / TK;
            #pragma unroll
            for (int j = 0; j < 4; ++j) {
                int ml = mbase + 16 * j;
                int m = m0 + ml, k = k0 + kl;
                float v = 0.f;
                if (m < M && k < K) v = A[(long)m * K + k];
                As[kl][ml] = v;
            }
        }
        // B tile (TK x TN)
        if (!transB) {
            int nl = tid % TN;
            int kbase = tid / TN;
            #pragma unroll
            for (int j = 0; j < 4; ++j) {
                int kl = kbase + 4 * j;
                int k = k0 + kl, n = n0 + nl;
                float v = 0.f;
                if (k < K && n < N) v = Bm[(long)k * N + n];
                Bs[kl][nl] = v;
            }
        } else {
            int kl = tid % TK;
            int nbase = tid / TK;
            #pragma unroll
            for (int j = 0; j < 4; ++j) {
                int nl = nbase + 16 * j;
                int k = k0 + kl, n = n0 + nl;
                float v = 0.f;
                if (k < K && n < N) v = Bm[(long)n * K + k];
                Bs[kl][nl] = v;
            }
        }
        __syncthreads();
        #pragma unroll
        for (int kk = 0; kk < TK; ++kk) {
            float a_[4], b_[4];
            #pragma unroll
            for (int i = 0; i < 4; ++i) a_[i] = As[kk][ty * 4 + i];
            #pragma unroll
            for (int j = 0; j < 4; ++j) b_[j] = Bs[kk][tx * 4 + j];
            #pragma unroll
            for (int i = 0; i < 4; ++i)
                #pragma unroll
                for (int j = 0; j < 4; ++j)
                    acc[i][j] += a_[i] * b_[j];
        }
        __syncthreads();
    }

    #pragma unroll
    for (int i = 0; i < 4; ++i) {
        int m = m0 + ty * 4 + i;
        if (m >= M) continue;
        #pragma unroll
        for (int j = 0; j < 4; ++j) {
            int n = n0 + tx * 4 + j;
            if (n >= N) continue;
            float v = acc[i][j];
            if (Dp)   v += Dp[(long)m * N + n];
            if (bias) v += bscale * bias[n];
            if (relu) v = fmaxf(v, 0.f);
            C[(long)m * N + n] = v;
        }
    }
}

// ---------------------------------------------------------------------------
// s1[b,k] = Σ_h G0[b,k,h]*w1_colsum[h]; s2[b,i] = Σ_h G0[b,i,h]*w2_colsum[h]
// ---------------------------------------------------------------------------
__global__ void s1s2_kernel(const float* __restrict__ G0,
                            const float* __restrict__ sm,
                            float* __restrict__ s12) {
    int r = blockIdx.x * blockDim.x + threadIdx.x;  // b*S + s
    if (r < Bc * Sc) {
        const float* g = G0 + (long)r * HDc;
        float a = 0.f, c = 0.f;
        for (int h = 0; h < HDc; ++h) {
            float v = g[h];
            a += v * sm[64 + h];
            c += v * sm[224 + h];
        }
        s12[2 * r]     = a;
        s12[2 * r + 1] = c;
    }
}

// ---------------------------------------------------------------------------
// A1[b,i,k] = (wadj[b,i,k] + s1[b,k] + s2[b,i] + sum_bh) / E
// ---------------------------------------------------------------------------
__global__ __launch_bounds__(256)
void a1_kernel(const float* __restrict__ wadj, const float* __restrict__ s12,
               const float* __restrict__ sm, float* __restrict__ A1) {
    int idx = blockIdx.x * 256 + threadIdx.x;
    const int total = Bc * Sc * Sc;
    if (idx < total) {
        int k  = idx % Sc;
        int bi = idx / Sc;       // b*S + i
        int b  = bi / Sc;
        float v = wadj[idx] + s12[2 * (b * Sc + k)] + s12[2 * bi + 1] + sm[384];
        A1[idx] = v * (1.0f / Ec);
    }
}

// X1 = concat(X, G0) along feature dim (450)
__global__ void concat_x1(const float* __restrict__ X, const float* __restrict__ G0,
                          float* __restrict__ X1) {
    int idx = blockIdx.x * 256 + threadIdx.x;
    const int total = Bc * Sc * (Dc + HDc);
    if (idx < total) {
        int r = idx / (Dc + HDc);
        int c = idx % (Dc + HDc);
        X1[idx] = (c < Dc) ? X[(long)r * Dc + c] : G0[(long)r * HDc + (c - Dc)];
    }
}

// Z = concat(G0, G1) + X  (feature dim 300)
__global__ void z_kernel(const float* __restrict__ X, const float* __restrict__ G0,
                         const float* __restrict__ G1, float* __restrict__ Z) {
    int idx = blockIdx.x * 256 + threadIdx.x;
    const int total = Bc * Sc * Dc;
    if (idx < total) {
        int r = idx / Dc;
        int c = idx % Dc;
        float g = (c < HDc) ? G0[(long)r * HDc + c] : G1[(long)r * HDc + (c - HDc)];
        Z[idx] = X[idx] + g;
    }
}

extern "C" void kernel_launch(void* const* d_in, const int* in_sizes, int n_in,
                              void* d_out, int out_size, void* d_ws, size_t ws_size,
                              hipStream_t stream) {
    const float* adj  = (const float*)d_in[0];
    const float* X    = (const float*)d_in[1];
    const float* W0   = (const float*)d_in[2];
    const float* b0   = (const float*)d_in[3];
    const float* W1   = (const float*)d_in[4];
    const float* b1   = (const float*)d_in[5];
    const float* Wh   = (const float*)d_in[6];
    const float* bh   = (const float*)d_in[7];
    const float* Wout = (const float*)d_in[8];
    const float* bout = (const float*)d_in[9];
    float* out = (float*)d_out;

    // workspace layout (floats)
    float* ws   = (float*)d_ws;
    float* sm   = ws;                         // 512
    float* A0   = sm + 512;                   // B*S*S   (reused as A1)
    float* wadj = A0 + Bc * Sc * Sc;          // B*S*S
    float* Y0   = wadj + Bc * Sc * Sc;        // B*S*D   (reused as Z)
    float* G0   = Y0 + Bc * Sc * Dc;          // B*S*HD
    float* s12  = G0 + Bc * Sc * HDc;         // B*S*2
    float* X1   = s12 + Bc * Sc * 2;          // B*S*450
    float* Y1   = X1 + Bc * Sc * (Dc + HDc);  // B*S*450
    float* G1   = Y1 + Bc * Sc * (Dc + HDc);  // B*S*HD

    const int nrows = Bc * Sc * Sc;           // 589824

    // 1) weight column sums
    prep_kernel<<<1, 512, 0, stream>>>(Wh, bh, sm);

    // 2) single pass over adj: A0 (scaled) + weighted sum for layer-1 adjacency
    reduce_adj<<<(nrows + 255) / 256, 256, 0, stream>>>(adj, sm, A0, wadj);

    // 3) Y0 = A0 @ X + X    (M=384,N=300,K=384, batched over B)
    gemm_kernel<<<dim3((Dc + TN - 1) / TN, (Sc + TM - 1) / TM, Bc), 256, 0, stream>>>(
        A0, X, X, nullptr, Y0, Sc, Dc, Sc,
        (long)Sc * Sc, (long)Sc * Dc, (long)Sc * Dc, (long)Sc * Dc, 0, 0.f, 0);

    // 4) G0 = relu(Y0 @ W0^T + 2*b0)   (N=150,K=300)
    gemm_kernel<<<dim3((HDc + TN - 1) / TN, (Sc + TM - 1) / TM, Bc), 256, 0, stream>>>(
        Y0, W0, nullptr, b0, G0, Sc, HDc, Dc,
        (long)Sc * Dc, 0, 0, (long)Sc * HDc, 1, 2.0f, 1);

    // 5) s1/s2 row sums of G0 against w1/w2 column sums
    s1s2_kernel<<<(Bc * Sc + 255) / 256, 256, 0, stream>>>(G0, sm, s12);

    // 6) A1 = (wadj + s1 + s2 + sum_bh)/E    (overwrites A0)
    a1_kernel<<<(nrows + 255) / 256, 256, 0, stream>>>(wadj, s12, sm, A0);

    // 7) X1 = concat(X, G0)
    {
        int tot = Bc * Sc * (Dc + HDc);
        concat_x1<<<(tot + 255) / 256, 256, 0, stream>>>(X, G0, X1);
    }

    // 8) Y1 = A1 @ X1 + X1   (N=450,K=384)
    gemm_kernel<<<dim3((Dc + HDc + TN - 1) / TN, (Sc + TM - 1) / TM, Bc), 256, 0, stream>>>(
        A0, X1, X1, nullptr, Y1, Sc, Dc + HDc, Sc,
        (long)Sc * Sc, (long)Sc * (Dc + HDc), (long)Sc * (Dc + HDc),
        (long)Sc * (Dc + HDc), 0, 0.f, 0);

    // 9) G1 = relu(Y1 @ W1^T + 2*b1)   (N=150,K=450)
    gemm_kernel<<<dim3((HDc + TN - 1) / TN, (Sc + TM - 1) / TM, Bc), 256, 0, stream>>>(
        Y1, W1, nullptr, b1, G1, Sc, HDc, Dc + HDc,
        (long)Sc * (Dc + HDc), 0, 0, (long)Sc * HDc, 1, 2.0f, 1);

    // 10) Z = concat(G0,G1) + X   (overwrites Y0)
    {
        int tot = Bc * Sc * Dc;
        z_kernel<<<(tot + 255) / 256, 256, 0, stream>>>(X, G0, G1, Y0);
    }

    // 11) out = Z @ Wout^T + bout   (flatten batch: M = B*S = 1536)
    gemm_kernel<<<dim3((Dc + TN - 1) / TN, (Bc * Sc + TM - 1) / TM, 1), 256, 0, stream>>>(
        Y0, Wout, nullptr, bout, out, Bc * Sc, Dc, Dc,
        0, 0, 0, 0, 1, 1.0f, 0);
}

// Round 2
// 292.073 us; speedup vs baseline: 2.0475x; 2.0475x over previous
//
#include <hip/hip_runtime.h>

// Problem constants
constexpr int Bc  = 4;
constexpr int Sc  = 384;
constexpr int Dc  = 300;
constexpr int Ec  = 50;
constexpr int HDc = 150;          // D / L
constexpr int WHC = 2*HDc + Ec;   // 350, Wh row length

// ---------------------------------------------------------------------------
// prep: column sums of Wh_e, Wh_1, Wh_2 and sum(bh) into small buffer
// layout (floats): [0..49] we_colsum, [64..213] w1_colsum, [224..373] w2_colsum,
//                  [384] sum(bh)
// ---------------------------------------------------------------------------
__global__ void prep_kernel(const float* __restrict__ Wh,
                            const float* __restrict__ bh,
                            float* __restrict__ sm) {
    int t = threadIdx.x;  // 512 threads
    if (t < Ec) {
        float s = 0.f;
        for (int e = 0; e < Ec; ++e) s += Wh[e*WHC + t];
        sm[t] = s;
    } else if (t >= 64 && t < 64 + HDc) {
        int h = t - 64;
        float s = 0.f;
        for (int e = 0; e < Ec; ++e) s += Wh[e*WHC + Ec + h];
        sm[t] = s;
    } else if (t >= 224 && t < 224 + HDc) {
        int h = t - 224;
        float s = 0.f;
        for (int e = 0; e < Ec; ++e) s += Wh[e*WHC + Ec + HDc + h];
        sm[t] = s;
    } else if (t == 384) {
        float s = 0.f;
        for (int e = 0; e < Ec; ++e) s += bh[e];
        sm[t] = s;
    }
}

// ---------------------------------------------------------------------------
// reduce_adj2: one coalesced pass over adj (B,S,S,E) via LDS staging.
// Block = 256 rows of 50 floats. float4 global loads (block base 51200 B,
// 16B aligned). LDS rows padded to 51 (gcd(19,32)=1 -> conflict-free reduce).
//   A0[row]   = (sum_e adj)/E ; wadj[row] = sum_e adj*we_colsum[e]
// ---------------------------------------------------------------------------
__global__ __launch_bounds__(256)
void reduce_adj2(const float* __restrict__ adj, const float* __restrict__ sm,
                 float* __restrict__ A0, float* __restrict__ wadj) {
    __shared__ float wec[64];
    __shared__ float tile[256 * 51];
    int t = threadIdx.x;
    if (t < Ec) wec[t] = sm[t];
    long base = (long)blockIdx.x * (256 * 50);
    const float4* p4 = (const float4*)(adj + base);
    for (int i = t; i < 3200; i += 256) {
        float4 v = p4[i];
        int e = 4 * i;
        const float* vp = (const float*)&v;
        #pragma unroll
        for (int j = 0; j < 4; ++j) {
            int ee = e + j;
            tile[(ee / 50) * 51 + (ee % 50)] = vp[j];
        }
    }
    __syncthreads();
    const float* row = tile + t * 51;
    float s = 0.f, w = 0.f;
    #pragma unroll
    for (int i = 0; i < 50; ++i) { float v = row[i]; s += v; w += v * wec[i]; }
    int r = blockIdx.x * 256 + t;
    A0[r]   = s * (1.0f / Ec);
    wadj[r] = w;
}

// ---------------------------------------------------------------------------
// gemm32: 32x32 tile, TK=32, 256 threads, 2x2 per thread, register-prefetch
// double buffering. C[b] = A[b] @ B(+T) [+ Dm[b]] [+ bscale*bias] [relu]
// ---------------------------------------------------------------------------
#define TS  32
#define LDP 34   // even stride: ds_read_b64-aligned, 2-way (free) bank aliasing

__global__ __launch_bounds__(256)
void gemm32(const float* __restrict__ A, const float* __restrict__ Bm,
            const float* __restrict__ Dm, const float* __restrict__ bias,
            float* __restrict__ C,
            int M, int N, int K,
            long sA, long sB, long sD, long sC,
            int transB, float bscale, int relu) {
    int b = blockIdx.z;
    A  += (long)b * sA;
    Bm += (long)b * sB;
    const float* Dp = Dm ? Dm + (long)b * sD : nullptr;
    C  += (long)b * sC;

    __shared__ float As[TS * LDP];
    __shared__ float Bs[TS * LDP];

    int tid = threadIdx.x;
    int tx = tid & 15, ty = tid >> 4;
    int m0 = blockIdx.y * TS, n0 = blockIdx.x * TS;

    float regA[4], regB[4];

    // tile loader: A tile (m-major), B tile
    auto loadA = [&](int k0) {
        #pragma unroll
        for (int j = 0; j < 4; ++j) {
            int i = tid + j * 256;          // 0..1023
            int ml = i >> 5, kl = i & 31;
            int m = m0 + ml, k = k0 + kl;
            regA[j] = (m < M && k < K) ? A[(long)m * K + k] : 0.f;
        }
    };
    auto loadB = [&](int k0) {
        if (!transB) {
            #pragma unroll
            for (int j = 0; j < 4; ++j) {
                int i = tid + j * 256;
                int kl = i >> 5, nl = i & 31;
                int k = k0 + kl, n = n0 + nl;
                regB[j] = (k < K && n < N) ? Bm[(long)k * N + n] : 0.f;
            }
        } else {
            #pragma unroll
            for (int j = 0; j < 4; ++j) {
                int i = tid + j * 256;
                int nl = i >> 5, kl = i & 31;
                int k = k0 + kl, n = n0 + nl;
                regB[j] = (n < N && k < K) ? Bm[(long)n * K + k] : 0.f;
            }
        }
    };
    auto stash = [&]() {
        #pragma unroll
        for (int j = 0; j < 4; ++j) {
            int i = tid + j * 256;
            int ml = i >> 5, kl = i & 31;
            As[kl * LDP + ml] = regA[j];
        }
        if (!transB) {
            #pragma unroll
            for (int j = 0; j < 4; ++j) {
                int i = tid + j * 256;
                int kl = i >> 5, nl = i & 31;
                Bs[kl * LDP + nl] = regB[j];
            }
        } else {
            #pragma unroll
            for (int j = 0; j < 4; ++j) {
                int i = tid + j * 256;
                int nl = i >> 5, kl = i & 31;
                Bs[kl * LDP + nl] = regB[j];
            }
        }
    };

    float acc00 = 0.f, acc01 = 0.f, acc10 = 0.f, acc11 = 0.f;

    loadA(0); loadB(0);
    for (int k0 = 0; k0 < K; k0 += TS) {
        __syncthreads();        // previous iter readers done
        stash();
        __syncthreads();
        if (k0 + TS < K) { loadA(k0 + TS); loadB(k0 + TS); }  // overlap w/ compute
        #pragma unroll
        for (int kk = 0; kk < TS; ++kk) {
            float2 av = *(const float2*)&As[kk * LDP + ty * 2];
            float2 bv = *(const float2*)&Bs[kk * LDP + tx * 2];
            acc00 += av.x * bv.x; acc01 += av.x * bv.y;
            acc10 += av.y * bv.x; acc11 += av.y * bv.y;
        }
    }

    float accs[2][2] = {{acc00, acc01}, {acc10, acc11}};
    #pragma unroll
    for (int i = 0; i < 2; ++i) {
        int m = m0 + ty * 2 + i;
        if (m >= M) continue;
        #pragma unroll
        for (int j = 0; j < 2; ++j) {
            int n = n0 + tx * 2 + j;
            if (n >= N) continue;
            float v = accs[i][j];
            if (Dp)   v += Dp[(long)m * N + n];
            if (bias) v += bscale * bias[n];
            if (relu) v = fmaxf(v, 0.f);
            C[(long)m * N + n] = v;
        }
    }
}

// ---------------------------------------------------------------------------
// s1[b,k] = sum_h G[b,k,h]*w1_colsum[h]; s2[b,i] = sum_h G[b,i,h]*w2_colsum[h]
// ---------------------------------------------------------------------------
__global__ void s1s2_kernel(const float* __restrict__ G0,
                            const float* __restrict__ sm,
                            float* __restrict__ s12) {
    int r = blockIdx.x * blockDim.x + threadIdx.x;
    if (r < Bc * Sc) {
        const float* g = G0 + (long)r * HDc;
        float a = 0.f, c = 0.f;
        for (int h = 0; h < HDc; ++h) {
            float v = g[h];
            a += v * sm[64 + h];
            c += v * sm[224 + h];
        }
        s12[2 * r]     = a;
        s12[2 * r + 1] = c;
    }
}

// A1[b,i,k] = (wadj + s1[b,k] + s2[b,i] + sum_bh) / E
__global__ __launch_bounds__(256)
void a1_kernel(const float* __restrict__ wadj, const float* __restrict__ s12,
               const float* __restrict__ sm, float* __restrict__ A1) {
    int idx = blockIdx.x * 256 + threadIdx.x;
    const int total = Bc * Sc * Sc;
    if (idx < total) {
        int k  = idx % Sc;
        int bi = idx / Sc;
        int b  = bi / Sc;
        float v = wadj[idx] + s12[2 * (b * Sc + k)] + s12[2 * bi + 1] + sm[384];
        A1[idx] = v * (1.0f / Ec);
    }
}

// X1 = concat(X, G0) along feature dim (450)
__global__ void concat_x1(const float* __restrict__ X, const float* __restrict__ G0,
                          float* __restrict__ X1) {
    int idx = blockIdx.x * 256 + threadIdx.x;
    const int total = Bc * Sc * (Dc + HDc);
    if (idx < total) {
        int r = idx / (Dc + HDc);
        int c = idx % (Dc + HDc);
        X1[idx] = (c < Dc) ? X[(long)r * Dc + c] : G0[(long)r * HDc + (c - Dc)];
    }
}

// Z = concat(G0, G1) + X
__global__ void z_kernel(const float* __restrict__ X, const float* __restrict__ G0,
                         const float* __restrict__ G1, float* __restrict__ Z) {
    int idx = blockIdx.x * 256 + threadIdx.x;
    const int total = Bc * Sc * Dc;
    if (idx < total) {
        int r = idx / Dc;
        int c = idx % Dc;
        float g = (c < HDc) ? G0[(long)r * HDc + c] : G1[(long)r * HDc + (c - HDc)];
        Z[idx] = X[idx] + g;
    }
}

extern "C" void kernel_launch(void* const* d_in, const int* in_sizes, int n_in,
                              void* d_out, int out_size, void* d_ws, size_t ws_size,
                              hipStream_t stream) {
    const float* adj  = (const float*)d_in[0];
    const float* X    = (const float*)d_in[1];
    const float* W0   = (const float*)d_in[2];
    const float* b0   = (const float*)d_in[3];
    const float* W1   = (const float*)d_in[4];
    const float* b1   = (const float*)d_in[5];
    const float* Wh   = (const float*)d_in[6];
    const float* bh   = (const float*)d_in[7];
    const float* Wout = (const float*)d_in[8];
    const float* bout = (const float*)d_in[9];
    float* out = (float*)d_out;

    // workspace layout (floats)
    float* ws   = (float*)d_ws;
    float* sm   = ws;                         // 512
    float* A0   = sm + 512;                   // B*S*S (later holds A1)
    float* wadj = A0 + Bc * Sc * Sc;          // B*S*S
    float* P0   = wadj + Bc * Sc * Sc;        // B*S*HD
    float* G0   = P0 + Bc * Sc * HDc;         // B*S*HD
    float* s12  = G0 + Bc * Sc * HDc;         // B*S*2
    float* X1   = s12 + Bc * Sc * 2;          // B*S*450
    float* P1   = X1 + Bc * Sc * (Dc + HDc);  // B*S*HD
    float* G1   = P1 + Bc * Sc * HDc;         // B*S*HD
    float* Z    = G1 + Bc * Sc * HDc;         // B*S*D

    const int nrows = Bc * Sc * Sc;           // 589824 = 2304*256

    // 1) weight column sums
    prep_kernel<<<1, 512, 0, stream>>>(Wh, bh, sm);

    // 2) coalesced pass over adj: A0 (scaled) + weighted edge reduction
    reduce_adj2<<<nrows / 256, 256, 0, stream>>>(adj, sm, A0, wadj);

    // 3) P0 = X @ W0^T   (M=1536,N=150,K=300)
    gemm32<<<dim3((HDc + TS - 1) / TS, (Bc * Sc + TS - 1) / TS, 1), 256, 0, stream>>>(
        X, W0, nullptr, nullptr, P0, Bc * Sc, HDc, Dc,
        0, 0, 0, 0, 1, 0.f, 0);

    // 4) G0 = relu(A0 @ P0 + P0 + 2*b0)   (batched, M=384,N=150,K=384)
    gemm32<<<dim3((HDc + TS - 1) / TS, (Sc + TS - 1) / TS, Bc), 256, 0, stream>>>(
        A0, P0, P0, b0, G0, Sc, HDc, Sc,
        (long)Sc * Sc, (long)Sc * HDc, (long)Sc * HDc, (long)Sc * HDc,
        0, 2.0f, 1);

    // 5) s1/s2 row reductions of G0
    s1s2_kernel<<<(Bc * Sc + 255) / 256, 256, 0, stream>>>(G0, sm, s12);

    // 6) A1 = (wadj + s1 + s2 + sum_bh)/E  (overwrites A0)
    a1_kernel<<<(nrows + 255) / 256, 256, 0, stream>>>(wadj, s12, sm, A0);

    // 7) X1 = concat(X, G0)
    {
        int tot = Bc * Sc * (Dc + HDc);
        concat_x1<<<(tot + 255) / 256, 256, 0, stream>>>(X, G0, X1);
    }

    // 8) P1 = X1 @ W1^T   (M=1536,N=150,K=450)
    gemm32<<<dim3((HDc + TS - 1) / TS, (Bc * Sc + TS - 1) / TS, 1), 256, 0, stream>>>(
        X1, W1, nullptr, nullptr, P1, Bc * Sc, HDc, Dc + HDc,
        0, 0, 0, 0, 1, 0.f, 0);

    // 9) G1 = relu(A1 @ P1 + P1 + 2*b1)   (batched)
    gemm32<<<dim3((HDc + TS - 1) / TS, (Sc + TS - 1) / TS, Bc), 256, 0, stream>>>(
        A0, P1, P1, b1, G1, Sc, HDc, Sc,
        (long)Sc * Sc, (long)Sc * HDc, (long)Sc * HDc, (long)Sc * HDc,
        0, 2.0f, 1);

    // 10) Z = concat(G0,G1) + X
    {
        int tot = Bc * Sc * Dc;
        z_kernel<<<(tot + 255) / 256, 256, 0, stream>>>(X, G0, G1, Z);
    }

    // 11) out = Z @ Wout^T + bout   (M=1536,N=300,K=300)
    gemm32<<<dim3((Dc + TS - 1) / TS, (Bc * Sc + TS - 1) / TS, 1), 256, 0, stream>>>(
        Z, Wout, nullptr, bout, out, Bc * Sc, Dc, Dc,
        0, 0, 0, 0, 1, 1.0f, 0);
}